// Round 1
// baseline (491.834 us; speedup 1.0000x reference)
//
#include <hip/hip_runtime.h>
#include <math.h>

// Problem constants (fixed by setup_inputs)
#define BB 128
#define KK 32
#define JJ 1152
#define II 8
#define ZZ 16
#define JC 16            // j's per block
#define JCH (JJ / JC)    // 72 chunks

#define N_USUM (BB * KK * ZZ)   // 65536
#define N_S    (BB * JJ)        // 147456
#define N_SACC (BB * KK * ZZ)   // 65536

// sum across the 16 z-lanes of a 16-lane group (lanes l = jj*16 + z)
__device__ __forceinline__ float group16_sum(float v) {
    v += __shfl_xor(v, 1);
    v += __shfl_xor(v, 2);
    v += __shfl_xor(v, 4);
    v += __shfl_xor(v, 8);
    return v;
}

// u[b,k,j,z] = sum_i x[b,j,i] * W[k,j,i,z]  with W fragment in registers
__device__ __forceinline__ float dot8(const float* __restrict__ xb, int j,
                                      const float w[8]) {
    const float4* xp = (const float4*)(xb + j * II);
    float4 a = xp[0], c = xp[1];
    float u = a.x * w[0];
    u = fmaf(a.y, w[1], u);
    u = fmaf(a.z, w[2], u);
    u = fmaf(a.w, w[3], u);
    u = fmaf(c.x, w[4], u);
    u = fmaf(c.y, w[5], u);
    u = fmaf(c.z, w[6], u);
    u = fmaf(c.w, w[7], u);
    return u;
}

// ---- Kernel A: usum[b,k,z] = sum_{j,i} x[b,j,i] * W[k,j,i,z] ----
extern "C" __global__ __launch_bounds__(256)
void kA(const float* __restrict__ x, const float* __restrict__ W,
        float* __restrict__ usum) {
    const int jcb  = blockIdx.x * JC;
    const int k    = blockIdx.y;
    const int t    = threadIdx.x;
    const int l    = t & 63;
    const int wave = t >> 6;
    const int jjg  = l >> 4;
    const int z    = l & 15;

    float w[4][8];
    {
        const float* Wk = W + (size_t)k * JJ * II * ZZ + (size_t)jcb * II * ZZ + z;
#pragma unroll
        for (int jt = 0; jt < 4; ++jt) {
            const float* wp = Wk + (jt * 4 + jjg) * II * ZZ;
#pragma unroll
            for (int i = 0; i < II; ++i) w[jt][i] = wp[i * ZZ];
        }
    }

    const int b0 = wave * 32;
    for (int b = b0; b < b0 + 32; ++b) {
        const float* xb = x + (size_t)b * JJ * II;
        float acc = 0.f;
#pragma unroll
        for (int jt = 0; jt < 4; ++jt)
            acc += dot8(xb, jcb + jt * 4 + jjg, w[jt]);
        acc += __shfl_xor(acc, 16);
        acc += __shfl_xor(acc, 32);
        if (l < 16) unsafeAtomicAdd(&usum[(b * KK + k) * ZZ + z], acc);
    }
}

// ---- Kernel B: S[b,j] = sum_k exp( dot_z(u, usum)/sqrt(Z) ) ----
extern "C" __global__ __launch_bounds__(256)
void kB(const float* __restrict__ x, const float* __restrict__ W,
        const float* __restrict__ usum, float* __restrict__ S) {
    const int jcb  = blockIdx.x * JC;
    const int k    = blockIdx.y;
    const int t    = threadIdx.x;
    const int l    = t & 63;
    const int wave = t >> 6;
    const int jjg  = l >> 4;
    const int z    = l & 15;

    float w[4][8];
    {
        const float* Wk = W + (size_t)k * JJ * II * ZZ + (size_t)jcb * II * ZZ + z;
#pragma unroll
        for (int jt = 0; jt < 4; ++jt) {
            const float* wp = Wk + (jt * 4 + jjg) * II * ZZ;
#pragma unroll
            for (int i = 0; i < II; ++i) w[jt][i] = wp[i * ZZ];
        }
    }

    const int b0 = wave * 32;
    for (int b = b0; b < b0 + 32; ++b) {
        const float us  = usum[(b * KK + k) * ZZ + z];
        const float* xb = x + (size_t)b * JJ * II;
#pragma unroll
        for (int jt = 0; jt < 4; ++jt) {
            float u  = dot8(xb, jcb + jt * 4 + jjg, w[jt]);
            float dp = group16_sum(u * us);
            float e  = __expf(dp * 0.25f);   // /sqrt(16)
            if (z == 0)
                unsafeAtomicAdd(&S[b * JJ + jcb + jt * 4 + jjg], e);
        }
    }
}

// ---- Kernel C: s[b,k,z] += u * ( exp(d)/S[b,j] + bias[k,j] ) ----
extern "C" __global__ __launch_bounds__(256)
void kC(const float* __restrict__ x, const float* __restrict__ W,
        const float* __restrict__ bias, const float* __restrict__ usum,
        const float* __restrict__ S, float* __restrict__ sacc) {
    const int jcb  = blockIdx.x * JC;
    const int k    = blockIdx.y;
    const int t    = threadIdx.x;
    const int l    = t & 63;
    const int wave = t >> 6;
    const int jjg  = l >> 4;
    const int z    = l & 15;

    float w[4][8];
    float bs[4];
    {
        const float* Wk = W + (size_t)k * JJ * II * ZZ + (size_t)jcb * II * ZZ + z;
#pragma unroll
        for (int jt = 0; jt < 4; ++jt) {
            const float* wp = Wk + (jt * 4 + jjg) * II * ZZ;
#pragma unroll
            for (int i = 0; i < II; ++i) w[jt][i] = wp[i * ZZ];
            bs[jt] = bias[k * JJ + jcb + jt * 4 + jjg];
        }
    }

    const int b0 = wave * 32;
    for (int b = b0; b < b0 + 32; ++b) {
        const float us  = usum[(b * KK + k) * ZZ + z];
        const float* xb = x + (size_t)b * JJ * II;
        float s_acc = 0.f;
#pragma unroll
        for (int jt = 0; jt < 4; ++jt) {
            int   j  = jcb + jt * 4 + jjg;
            float u  = dot8(xb, j, w[jt]);
            float dp = group16_sum(u * us);
            float e  = __expf(dp * 0.25f);
            float c  = e / S[b * JJ + j] + bs[jt];
            s_acc    = fmaf(u, c, s_acc);
        }
        s_acc += __shfl_xor(s_acc, 16);
        s_acc += __shfl_xor(s_acc, 32);
        if (l < 16) unsafeAtomicAdd(&sacc[(b * KK + k) * ZZ + z], s_acc);
    }
}

// ---- Kernel D: squash ----
extern "C" __global__ __launch_bounds__(256)
void kD(const float* __restrict__ sacc, float* __restrict__ out) {
    int p = blockIdx.x * blockDim.x + threadIdx.x;
    if (p >= BB * KK) return;
    const float4* sp = (const float4*)(sacc + (size_t)p * ZZ);
    float4 v0 = sp[0], v1 = sp[1], v2 = sp[2], v3 = sp[3];
    float nsq = v0.x * v0.x + v0.y * v0.y + v0.z * v0.z + v0.w * v0.w
              + v1.x * v1.x + v1.y * v1.y + v1.z * v1.z + v1.w * v1.w
              + v2.x * v2.x + v2.y * v2.y + v2.z * v2.z + v2.w * v2.w
              + v3.x * v3.x + v3.y * v3.y + v3.z * v3.z + v3.w * v3.w;
    float n = sqrtf(nsq);
    float scale = (1.f - 1.f / (__expf(n) + 1e-20f)) / (n + 1e-20f);
    v0.x *= scale; v0.y *= scale; v0.z *= scale; v0.w *= scale;
    v1.x *= scale; v1.y *= scale; v1.z *= scale; v1.w *= scale;
    v2.x *= scale; v2.y *= scale; v2.z *= scale; v2.w *= scale;
    v3.x *= scale; v3.y *= scale; v3.z *= scale; v3.w *= scale;
    float4* op = (float4*)(out + (size_t)p * ZZ);
    op[0] = v0; op[1] = v1; op[2] = v2; op[3] = v3;
}

extern "C" void kernel_launch(void* const* d_in, const int* in_sizes, int n_in,
                              void* d_out, int out_size, void* d_ws, size_t ws_size,
                              hipStream_t stream) {
    const float* x    = (const float*)d_in[0];
    const float* W    = (const float*)d_in[1];
    const float* bias = (const float*)d_in[2];
    float*       out  = (float*)d_out;

    float* ws    = (float*)d_ws;
    float* usum  = ws;                       // [B,K,Z]
    float* S     = ws + N_USUM;              // [B,J]
    float* saccp = ws + N_USUM + N_S;        // [B,K,Z]

    hipMemsetAsync(d_ws, 0, (size_t)(N_USUM + N_S + N_SACC) * sizeof(float), stream);

    dim3 grid(JCH, KK);
    kA<<<grid, 256, 0, stream>>>(x, W, usum);
    kB<<<grid, 256, 0, stream>>>(x, W, usum, S);
    kC<<<grid, 256, 0, stream>>>(x, W, bias, usum, S, saccp);
    kD<<<(BB * KK + 255) / 256, 256, 0, stream>>>(saccp, out);
}

// Round 2
// 202.788 us; speedup vs baseline: 2.4254x; 2.4254x over previous
//
#include <hip/hip_runtime.h>
#include <math.h>

// Problem constants
#define BB 128
#define KK 32
#define JJ 1152
#define II 8
#define ZZ 16

#define JCB 32              // j's per block
#define NJC (JJ / JCB)      // 36 chunks
#define JPW (JCB / 4)       // 8 j's per wave (4 waves/block)
#define BCB 64              // b's per block (one per lane)
#define NBC (BB / BCB)      // 2

#define XROW (JCB * II + 1) // 257 dwords per b-row in LDS (257%32==1 -> conflict-free)

#define N_USUM (KK * ZZ * BB)   // layout [k][z][b]
#define N_S    (JJ * BB)        // layout [j][b]
#define N_SACC (KK * ZZ * BB)   // layout [k][z][b]

// Stage x[bc*64 .. +64)[jcb .. jcb+32)[0..8) into LDS, coalesced.
__device__ __forceinline__ void stage_x(const float* __restrict__ x, float* xs,
                                        int jcb, int bc) {
    const int t  = threadIdx.x;
    const int q  = t & 3;        // 4 threads per b-row
    const int bp = t >> 2;       // 0..63
    const float4* gsrc = (const float4*)(x + (size_t)(bc * BCB + bp) * JJ * II + jcb * II);
#pragma unroll
    for (int it = 0; it < 16; ++it) {
        int c4 = it * 4 + q;             // float4 index 0..63 within the row
        float4 v = gsrc[c4];
        int base = bp * XROW + c4 * 4;   // scalar stores (row stride 257 is odd)
        xs[base + 0] = v.x; xs[base + 1] = v.y;
        xs[base + 2] = v.z; xs[base + 3] = v.w;
    }
}

// Compute u[z] for one (b, j): 8 i-steps, W via wave-uniform (scalar) loads.
__device__ __forceinline__ void compute_uz(const float* __restrict__ Wj,
                                           const float* __restrict__ xr,
                                           float uz[ZZ]) {
#pragma unroll
    for (int z = 0; z < ZZ; ++z) uz[z] = 0.f;
#pragma unroll
    for (int i = 0; i < II; ++i) {
        float xi = xr[i];                                  // ds_read_b32, conflict-free
        const float4* wp = (const float4*)(Wj + i * ZZ);   // uniform -> s_load
        float4 w0 = wp[0], w1 = wp[1], w2 = wp[2], w3 = wp[3];
        uz[0]  = fmaf(xi, w0.x, uz[0]);  uz[1]  = fmaf(xi, w0.y, uz[1]);
        uz[2]  = fmaf(xi, w0.z, uz[2]);  uz[3]  = fmaf(xi, w0.w, uz[3]);
        uz[4]  = fmaf(xi, w1.x, uz[4]);  uz[5]  = fmaf(xi, w1.y, uz[5]);
        uz[6]  = fmaf(xi, w1.z, uz[6]);  uz[7]  = fmaf(xi, w1.w, uz[7]);
        uz[8]  = fmaf(xi, w2.x, uz[8]);  uz[9]  = fmaf(xi, w2.y, uz[9]);
        uz[10] = fmaf(xi, w2.z, uz[10]); uz[11] = fmaf(xi, w2.w, uz[11]);
        uz[12] = fmaf(xi, w3.x, uz[12]); uz[13] = fmaf(xi, w3.y, uz[13]);
        uz[14] = fmaf(xi, w3.z, uz[14]); uz[15] = fmaf(xi, w3.w, uz[15]);
    }
}

// ---- Pass A: usum[k][z][b] = sum_j u[b,k,j,z] ----
extern "C" __global__ __launch_bounds__(256)
void kA(const float* __restrict__ x, const float* __restrict__ W,
        float* __restrict__ usum) {
    __shared__ float xs[BCB * XROW];
    const int jcb = blockIdx.x * JCB;
    const int k   = blockIdx.y;
    const int bc  = blockIdx.z;
    stage_x(x, xs, jcb, bc);
    __syncthreads();

    const int t  = threadIdx.x;
    const int w  = __builtin_amdgcn_readfirstlane(t >> 6);
    const int lb = t & 63;
    const int bg = bc * BCB + lb;

    float acc[ZZ];
#pragma unroll
    for (int z = 0; z < ZZ; ++z) acc[z] = 0.f;

    const float* Wk = W + ((size_t)k * JJ + jcb + w * JPW) * II * ZZ;
    for (int jl = 0; jl < JPW; ++jl) {
        float uz[ZZ];
        compute_uz(Wk + jl * II * ZZ, &xs[lb * XROW + (w * JPW + jl) * II], uz);
#pragma unroll
        for (int z = 0; z < ZZ; ++z) acc[z] += uz[z];
    }
#pragma unroll
    for (int z = 0; z < ZZ; ++z)
        unsafeAtomicAdd(&usum[(k * ZZ + z) * BB + bg], acc[z]);
}

// ---- Pass B: S[j][b] = sum_k exp( dot_z(u, usum) / 4 ) ----
extern "C" __global__ __launch_bounds__(256)
void kB(const float* __restrict__ x, const float* __restrict__ W,
        const float* __restrict__ usum, float* __restrict__ S) {
    __shared__ float xs[BCB * XROW];
    const int jcb = blockIdx.x * JCB;
    const int k   = blockIdx.y;
    const int bc  = blockIdx.z;
    stage_x(x, xs, jcb, bc);
    __syncthreads();

    const int t  = threadIdx.x;
    const int w  = __builtin_amdgcn_readfirstlane(t >> 6);
    const int lb = t & 63;
    const int bg = bc * BCB + lb;

    float us[ZZ];
#pragma unroll
    for (int z = 0; z < ZZ; ++z) us[z] = usum[(k * ZZ + z) * BB + bg];

    const float* Wk = W + ((size_t)k * JJ + jcb + w * JPW) * II * ZZ;
    for (int jl = 0; jl < JPW; ++jl) {
        const int j = jcb + w * JPW + jl;
        float uz[ZZ];
        compute_uz(Wk + jl * II * ZZ, &xs[lb * XROW + (w * JPW + jl) * II], uz);
        float dp = 0.f;
#pragma unroll
        for (int z = 0; z < ZZ; ++z) dp = fmaf(uz[z], us[z], dp);
        float e = __expf(dp * 0.25f);   // / sqrt(Z=16)
        unsafeAtomicAdd(&S[j * BB + bg], e);
    }
}

// ---- Pass C: sacc[k][z][b] += u * ( exp(d)/S + bias ) ----
extern "C" __global__ __launch_bounds__(256)
void kC(const float* __restrict__ x, const float* __restrict__ W,
        const float* __restrict__ bias, const float* __restrict__ usum,
        const float* __restrict__ S, float* __restrict__ sacc) {
    __shared__ float xs[BCB * XROW];
    const int jcb = blockIdx.x * JCB;
    const int k   = blockIdx.y;
    const int bc  = blockIdx.z;
    stage_x(x, xs, jcb, bc);
    __syncthreads();

    const int t  = threadIdx.x;
    const int w  = __builtin_amdgcn_readfirstlane(t >> 6);
    const int lb = t & 63;
    const int bg = bc * BCB + lb;

    float us[ZZ];
#pragma unroll
    for (int z = 0; z < ZZ; ++z) us[z] = usum[(k * ZZ + z) * BB + bg];

    float sc[ZZ];
#pragma unroll
    for (int z = 0; z < ZZ; ++z) sc[z] = 0.f;

    const float* Wk = W + ((size_t)k * JJ + jcb + w * JPW) * II * ZZ;
    for (int jl = 0; jl < JPW; ++jl) {
        const int j = jcb + w * JPW + jl;
        float uz[ZZ];
        compute_uz(Wk + jl * II * ZZ, &xs[lb * XROW + (w * JPW + jl) * II], uz);
        float dp = 0.f;
#pragma unroll
        for (int z = 0; z < ZZ; ++z) dp = fmaf(uz[z], us[z], dp);
        float e  = __expf(dp * 0.25f);
        float Sv = S[j * BB + bg];                       // coalesced
        float bj = bias[k * JJ + j];                     // uniform -> s_load
        float ci = fmaf(e, __builtin_amdgcn_rcpf(Sv), bj);
#pragma unroll
        for (int z = 0; z < ZZ; ++z) sc[z] = fmaf(uz[z], ci, sc[z]);
    }
#pragma unroll
    for (int z = 0; z < ZZ; ++z)
        unsafeAtomicAdd(&sacc[(k * ZZ + z) * BB + bg], sc[z]);
}

// ---- Pass D: squash, sacc[k][z][b] -> out[b][k][z] ----
extern "C" __global__ __launch_bounds__(256)
void kD(const float* __restrict__ sacc, float* __restrict__ out) {
    int p = blockIdx.x * blockDim.x + threadIdx.x;
    if (p >= KK * BB) return;
    int k = p >> 7;       // /128
    int b = p & 127;
    float v[ZZ];
    float nsq = 0.f;
#pragma unroll
    for (int z = 0; z < ZZ; ++z) {
        v[z] = sacc[(k * ZZ + z) * BB + b];   // coalesced per z
        nsq  = fmaf(v[z], v[z], nsq);
    }
    float n = sqrtf(nsq);
    float scale = (1.f - 1.f / (__expf(n) + 1e-20f)) / (n + 1e-20f);
#pragma unroll
    for (int z = 0; z < ZZ; ++z)
        out[((size_t)b * KK + k) * ZZ + z] = v[z] * scale;
}

extern "C" void kernel_launch(void* const* d_in, const int* in_sizes, int n_in,
                              void* d_out, int out_size, void* d_ws, size_t ws_size,
                              hipStream_t stream) {
    const float* x    = (const float*)d_in[0];
    const float* W    = (const float*)d_in[1];
    const float* bias = (const float*)d_in[2];
    float*       out  = (float*)d_out;

    float* ws    = (float*)d_ws;
    float* usum  = ws;                       // [K][Z][B]
    float* S     = ws + N_USUM;              // [J][B]
    float* saccp = ws + N_USUM + N_S;        // [K][Z][B]

    hipMemsetAsync(d_ws, 0, (size_t)(N_USUM + N_S + N_SACC) * sizeof(float), stream);

    dim3 grid(NJC, KK, NBC);
    kA<<<grid, 256, 0, stream>>>(x, W, usum);
    kB<<<grid, 256, 0, stream>>>(x, W, usum, S);
    kC<<<grid, 256, 0, stream>>>(x, W, bias, usum, S, saccp);
    kD<<<(KK * BB + 255) / 256, 256, 0, stream>>>(saccp, out);
}